// Round 3
// baseline (815.015 us; speedup 1.0000x reference)
//
#include <hip/hip_runtime.h>

typedef __attribute__((ext_vector_type(4))) float f32x4;
typedef __attribute__((ext_vector_type(8))) short bf16x8;  // 8 bf16 = 4 VGPRs

#define HDIM 128

// fp32 -> bf16 round-to-nearest-even
__device__ __forceinline__ short f2bf(float f) {
  union { float fv; unsigned u; } v; v.fv = f;
  unsigned u = v.u;
  u += 0x7fffu + ((u >> 16) & 1u);
  return (short)(u >> 16);
}

// out[b][g] = sum_k h[b][k] * W[g][k] + x[b][g]
// MFMA: A = W (M-dim = g), B = h^T (N-dim = b), x fed as C-in (D = W*h + x).
// C/D layout: col = lane&15 -> b, row = (lane>>4)*4 + reg -> g
//   => lane's 4 acc regs = 4 contiguous g's of one output row: float4 I/O.
//
// Round-3 structure: 256 threads, (256,4) => 120ish VGPR bucket (round 2's
// (512,8) forced 64-total regs and spilled: hbm_bytes 1.08->2.61 GB, 2.5x dur).
// Software-pipelined in PAIRS of 64-row tiles: while computing/storing the
// current pair, the next pair's raw fp32 h loads are in flight (pure per-wave
// MLP, no occupancy change). All arrays statically indexed (no scratch).
__global__ __launch_bounds__(256, 4) void lrc_mfma_kernel(
    const float* __restrict__ xp,
    const float* __restrict__ hp,
    const float* __restrict__ Wp,
    float* __restrict__ outp,
    int num_pairs)  // pairs of 64-row tiles (128 rows per pair)
{
  __shared__ short wlds[32 * 64 * 8];  // 32 frags x 64 lanes x 8 bf16 = 32 KB

  const int tid  = (int)threadIdx.x;
  const int wave = tid >> 6;   // 0..3
  const int lane = tid & 63;
  const int l15  = lane & 15;
  const int lq   = lane >> 4;

  // ---- Stage W as 32 bf16 A-fragments in LDS (once per block). f = gt*4 + kt ----
  // A-frag: lane holds W[gt*16 + (lane&15)][kt*32 + (lane>>4)*8 + e], e=0..7
  #pragma unroll
  for (int i = 0; i < 8; ++i) {
    const int f  = wave * 8 + i;
    const int gt = f >> 2;
    const int kt = f & 3;
    const float* wrow = Wp + (gt * 16 + l15) * HDIM + kt * 32 + lq * 8;
    const f32x4 w0 = *(const f32x4*)(wrow);
    const f32x4 w1 = *(const f32x4*)(wrow + 4);
    bf16x8 wf;
    wf[0] = f2bf(w0[0]); wf[1] = f2bf(w0[1]); wf[2] = f2bf(w0[2]); wf[3] = f2bf(w0[3]);
    wf[4] = f2bf(w1[0]); wf[5] = f2bf(w1[1]); wf[6] = f2bf(w1[2]); wf[7] = f2bf(w1[3]);
    *(bf16x8*)(&wlds[(f * 64 + lane) * 8]) = wf;  // lane-contiguous: conflict-free b128
  }
  __syncthreads();

  const int stride = (int)gridDim.x;
  const long laneoff = (long)(wave * 16 + l15) * HDIM + lq * 8;  // per-lane h offset within a pair-tile

  int pair = (int)blockIdx.x;

  // ---- Prologue: issue raw h loads for the first pair ----
  f32x4 hraw[2][8];  // 64 VGPRs, statically indexed only
  {
    const float* h0 = hp + (long)pair * 128 * HDIM + laneoff;        // tile 0
    const float* h1 = h0 + 64 * HDIM;                                // tile 1
    #pragma unroll
    for (int i = 0; i < 4; ++i) {
      hraw[0][2*i]   = *(const f32x4*)(h0 + i * 32);
      hraw[0][2*i+1] = *(const f32x4*)(h0 + i * 32 + 4);
      hraw[1][2*i]   = *(const f32x4*)(h1 + i * 32);
      hraw[1][2*i+1] = *(const f32x4*)(h1 + i * 32 + 4);
    }
  }

  while (pair < num_pairs) {
    const int next = pair + stride;

    // ---- Convert current pair's h to bf16 fragments (frees hraw for prefetch) ----
    bf16x8 hf[2][4];  // 32 VGPRs
    #pragma unroll
    for (int t = 0; t < 2; ++t) {
      #pragma unroll
      for (int kt = 0; kt < 4; ++kt) {
        const f32x4 a = hraw[t][2*kt];
        const f32x4 b = hraw[t][2*kt+1];
        hf[t][kt][0] = f2bf(a[0]); hf[t][kt][1] = f2bf(a[1]);
        hf[t][kt][2] = f2bf(a[2]); hf[t][kt][3] = f2bf(a[3]);
        hf[t][kt][4] = f2bf(b[0]); hf[t][kt][5] = f2bf(b[1]);
        hf[t][kt][6] = f2bf(b[2]); hf[t][kt][7] = f2bf(b[3]);
      }
    }

    // ---- Prefetch next pair's raw h (in flight during compute+store below) ----
    if (next < num_pairs) {
      const float* h0 = hp + (long)next * 128 * HDIM + laneoff;
      const float* h1 = h0 + 64 * HDIM;
      #pragma unroll
      for (int i = 0; i < 4; ++i) {
        hraw[0][2*i]   = *(const f32x4*)(h0 + i * 32);
        hraw[0][2*i+1] = *(const f32x4*)(h0 + i * 32 + 4);
        hraw[1][2*i]   = *(const f32x4*)(h1 + i * 32);
        hraw[1][2*i+1] = *(const f32x4*)(h1 + i * 32 + 4);
      }
    }

    // ---- Compute + store both tiles of the current pair (x as MFMA C-in) ----
    const long rowbase = (long)pair * 128 + wave * 16 + l15;
    #pragma unroll
    for (int t = 0; t < 2; ++t) {
      const float* xrow = xp + (rowbase + t * 64) * HDIM;
      float* orow = outp + (rowbase + t * 64) * HDIM;
      #pragma unroll
      for (int gt = 0; gt < 8; ++gt) {
        f32x4 acc = *(const f32x4*)(xrow + gt * 16 + lq * 4);  // D = W*h + x
        #pragma unroll
        for (int kt = 0; kt < 4; ++kt) {
          const bf16x8 wf = *(const bf16x8*)(&wlds[((gt * 4 + kt) * 64 + lane) * 8]);
          acc = __builtin_amdgcn_mfma_f32_16x16x32_bf16(wf, hf[t][kt], acc, 0, 0, 0);
        }
        *(f32x4*)(orow + gt * 16 + lq * 4) = acc;
      }
    }

    pair = next;
  }
}

extern "C" void kernel_launch(void* const* d_in, const int* in_sizes, int n_in,
                              void* d_out, int out_size, void* d_ws, size_t ws_size,
                              hipStream_t stream) {
  const float* xp = (const float*)d_in[0];  // x_projected_t (B,H) fp32
  const float* hp = (const float*)d_in[1];  // h_prev        (B,H) fp32
  const float* Wp = (const float*)d_in[2];  // W_hh          (H,H) fp32
  float* op = (float*)d_out;                // h_next        (B,H) fp32

  const int B = in_sizes[0] / HDIM;         // 1048576
  const int num_pairs = B / 128;            // 8192 pairs (2 x 64-row tiles)
  const int grid = 1024;                    // 8 pairs/block, uniform (no tail)

  hipLaunchKernelGGL(lrc_mfma_kernel, dim3(grid), dim3(256), 0, stream,
                     xp, hp, Wp, op, num_pairs);
}

// Round 4
// 315.715 us; speedup vs baseline: 2.5815x; 2.5815x over previous
//
#include <hip/hip_runtime.h>

typedef __attribute__((ext_vector_type(4))) float f32x4;
typedef __attribute__((ext_vector_type(8))) short bf16x8;  // 8 bf16 = 4 VGPRs

#define HDIM 128

// fp32 -> bf16 round-to-nearest-even
__device__ __forceinline__ short f2bf(float f) {
  union { float fv; unsigned u; } v; v.fv = f;
  unsigned u = v.u;
  u += 0x7fffu + ((u >> 16) & 1u);
  return (short)(u >> 16);
}

// out[b][g] = sum_k h[b][k] * W[g][k] + x[b][g]
// MFMA: A = W (M-dim = g), B = h^T (N-dim = b), x fed as C-in (D = W*h + x).
// C/D layout: col = lane&15 -> b, row = (lane>>4)*4 + reg -> g
//   => lane's 4 acc regs = 4 contiguous g's of one output row: float4 I/O.
//
// Round 4 = round 1's proven structure (296.7 us; 256 thr, natural VGPR
// allocation -- NO min-waves launch bound: (256,4)/(512,8) both forced
// spills, +1.5 GB scratch traffic, 2.5x dur) with two byte-neutral tweaks:
//   - x as MFMA C-in: deletes xv[8] (32 VGPR) + 8 v_add per tile
//   - nontemporal loads/stores: h/x/out are touch-once streams; keep them
//     from allocating through L2/L3 (write-allocate churn on out).
// Occupancy proven NOT the lever (R1 21% vs R2 79%: same true BW); bytes are.
__global__ __launch_bounds__(256) void lrc_mfma_kernel(
    const float* __restrict__ xp,
    const float* __restrict__ hp,
    const float* __restrict__ Wp,
    float* __restrict__ outp,
    int num_tiles)  // tiles of 64 rows (4 waves x 16 rows)
{
  __shared__ short wlds[32 * 64 * 8];  // 32 frags x 64 lanes x 8 bf16 = 32 KB

  const int tid  = (int)threadIdx.x;
  const int wave = tid >> 6;   // 0..3
  const int lane = tid & 63;
  const int l15  = lane & 15;
  const int lq   = lane >> 4;

  // ---- Stage W as 32 bf16 A-fragments in LDS (once per block). f = gt*4 + kt ----
  // A-frag: lane holds W[gt*16 + (lane&15)][kt*32 + (lane>>4)*8 + e], e=0..7
  #pragma unroll
  for (int i = 0; i < 8; ++i) {
    const int f  = wave * 8 + i;
    const int gt = f >> 2;
    const int kt = f & 3;
    const float* wrow = Wp + (gt * 16 + l15) * HDIM + kt * 32 + lq * 8;
    const f32x4 w0 = *(const f32x4*)(wrow);
    const f32x4 w1 = *(const f32x4*)(wrow + 4);
    bf16x8 wf;
    wf[0] = f2bf(w0[0]); wf[1] = f2bf(w0[1]); wf[2] = f2bf(w0[2]); wf[3] = f2bf(w0[3]);
    wf[4] = f2bf(w1[0]); wf[5] = f2bf(w1[1]); wf[6] = f2bf(w1[2]); wf[7] = f2bf(w1[3]);
    *(bf16x8*)(&wlds[(f * 64 + lane) * 8]) = wf;  // lane-contiguous: conflict-free b128
  }
  __syncthreads();

  for (int bt = (int)blockIdx.x; bt < num_tiles; bt += (int)gridDim.x) {
    const long row = (long)bt * 64 + wave * 16 + l15;   // this lane's batch row
    const float* hrow = hp + row * HDIM;

    // B-operand fragments from h: lane holds h[row][kt*32 + lq*8 + e] (contiguous 32B)
    bf16x8 hf[4];
    #pragma unroll
    for (int kt = 0; kt < 4; ++kt) {
      const f32x4 a = __builtin_nontemporal_load((const f32x4*)(hrow + kt * 32 + lq * 8));
      const f32x4 b = __builtin_nontemporal_load((const f32x4*)(hrow + kt * 32 + lq * 8) + 1);
      hf[kt][0] = f2bf(a[0]); hf[kt][1] = f2bf(a[1]);
      hf[kt][2] = f2bf(a[2]); hf[kt][3] = f2bf(a[3]);
      hf[kt][4] = f2bf(b[0]); hf[kt][5] = f2bf(b[1]);
      hf[kt][6] = f2bf(b[2]); hf[kt][7] = f2bf(b[3]);
    }

    const float* xrow = xp + row * HDIM;
    float* orow = outp + row * HDIM;
    #pragma unroll
    for (int gt = 0; gt < 8; ++gt) {
      // x as MFMA C-in: D = W*h + x (no xv[] array, no epilogue adds)
      f32x4 acc = __builtin_nontemporal_load((const f32x4*)(xrow + gt * 16 + lq * 4));
      #pragma unroll
      for (int kt = 0; kt < 4; ++kt) {
        const bf16x8 wf = *(const bf16x8*)(&wlds[((gt * 4 + kt) * 64 + lane) * 8]);
        acc = __builtin_amdgcn_mfma_f32_16x16x32_bf16(wf, hf[kt], acc, 0, 0, 0);
      }
      __builtin_nontemporal_store(acc, (f32x4*)(orow + gt * 16 + lq * 4));
    }
  }
}

extern "C" void kernel_launch(void* const* d_in, const int* in_sizes, int n_in,
                              void* d_out, int out_size, void* d_ws, size_t ws_size,
                              hipStream_t stream) {
  const float* xp = (const float*)d_in[0];  // x_projected_t (B,H) fp32
  const float* hp = (const float*)d_in[1];  // h_prev        (B,H) fp32
  const float* Wp = (const float*)d_in[2];  // W_hh          (H,H) fp32
  float* op = (float*)d_out;                // h_next        (B,H) fp32

  const int B = in_sizes[0] / HDIM;         // 1048576
  const int num_tiles = B / 64;             // 16384 tiles of 64 rows
  const int grid = 2048;                    // 8 tiles/block, uniform (no tail)

  hipLaunchKernelGGL(lrc_mfma_kernel, dim3(grid), dim3(256), 0, stream,
                     xp, hp, Wp, op, num_tiles);
}